// Round 1
// baseline (3875.186 us; speedup 1.0000x reference)
//
#include <hip/hip_runtime.h>
#include <stdint.h>

#define N_TOT 10647
#define MAXW  167   // ceil(10647/64)

// YOLOv3 COCO anchors, grouped by head: [0..2]=13x13, [3..5]=26x26, [6..8]=52x52
__constant__ float c_aw[9] = {116.f,156.f,373.f, 30.f,62.f,59.f, 10.f,16.f,33.f};
__constant__ float c_ah[9] = { 90.f,198.f,326.f, 61.f,45.f,119.f, 13.f,30.f,23.f};

__device__ __forceinline__ float sigmoidf_(float x) { return 1.0f / (1.0f + expf(-x)); }

// One thread per box: decode (cx,cy,w,h), conf, argmax class, validity.
__global__ void decode_kernel(const float* __restrict__ p0,
                              const float* __restrict__ p1,
                              const float* __restrict__ p2,
                              float* __restrict__ box, float* __restrict__ conf,
                              float* __restrict__ score, int* __restrict__ cls,
                              int* __restrict__ dV)
{
    int n = blockIdx.x * blockDim.x + threadIdx.x;
    if (n >= N_TOT) return;
    const float* p; int H, base, lvl; float stride;
    if (n < 507)       { p = p0; H = 13; base = 0;    stride = 32.f; lvl = 0; }
    else if (n < 2535) { p = p1; H = 26; base = 507;  stride = 16.f; lvl = 1; }
    else               { p = p2; H = 52; base = 2535; stride = 8.f;  lvl = 2; }
    int m   = n - base;
    int HW  = H * H;
    int a   = m / HW;
    int rem = m - a * HW;
    int gy  = rem / H;
    int gx  = rem - gy * H;
    const float* q = p + (size_t)(a * 85) * HW + rem;
    float tx = q[0];
    float ty = q[(size_t)HW];
    float tw = q[(size_t)2*HW];
    float th = q[(size_t)3*HW];
    float tc = q[(size_t)4*HW];
    // argmax over 80 class logits (first max wins, like jnp.argmax)
    float best = q[(size_t)5*HW]; int bi = 0;
    for (int c = 1; c < 80; ++c) {
        float v = q[(size_t)(5+c)*HW];
        if (v > best) { best = v; bi = c; }
    }
    float cx = (sigmoidf_(tx) + (float)gx) * stride;
    float cy = (sigmoidf_(ty) + (float)gy) * stride;
    // exp(t)*(anchor/stride)*stride == exp(t)*anchor exactly (stride is a power of 2)
    float bw = expf(tw) * c_aw[lvl*3 + a];
    float bh = expf(th) * c_ah[lvl*3 + a];
    float cf = sigmoidf_(tc);
    box[n*4+0] = cx; box[n*4+1] = cy; box[n*4+2] = bw; box[n*4+3] = bh;
    conf[n] = cf;
    cls[n]  = bi;
    bool valid = (cf >= 0.5f);
    score[n] = valid ? cf : -1.0f;
    if (valid) atomicAdd(dV, 1);
}

// Stable descending rank among valid boxes; scatter order[rank]=i.
__global__ void rank_kernel(const float* __restrict__ score, int* __restrict__ order)
{
    int i = blockIdx.x * blockDim.x + threadIdx.x;
    if (i >= N_TOT) return;
    float si = score[i];
    if (si < 0.0f) return;          // invalid: lands past V, row is zeroed anyway
    int r = 0;
    for (int j = 0; j < N_TOT; ++j) {
        float sj = score[j];
        r += (sj > si) ? 1 : ((sj == si && j < i) ? 1 : 0);
    }
    order[r] = i;
}

// Gather sorted corner/area/class arrays for the IoU pass.
__global__ void gather_kernel(const float* __restrict__ box, const int* __restrict__ cls,
                              const int* __restrict__ order, const int* __restrict__ dV,
                              float* __restrict__ sx1, float* __restrict__ sy1,
                              float* __restrict__ sx2, float* __restrict__ sy2,
                              float* __restrict__ sarea, int* __restrict__ scls)
{
    int r = blockIdx.x * blockDim.x + threadIdx.x;
    int V = *dV;
    if (r >= V) return;
    int i = order[r];
    float cx = box[i*4+0], cy = box[i*4+1], w = box[i*4+2], h = box[i*4+3];
    float hw = w * 0.5f, hh = h * 0.5f;
    sx1[r] = cx - hw; sy1[r] = cy - hh;
    sx2[r] = cx + hw; sy2[r] = cy + hh;
    sarea[r] = w * h;
    scls[r]  = cls[i];
}

// Suppression-candidate bitmask: mask[i][jw] bit b set iff j=jw*64+b > i,
// same class, IoU > 0.5. Lanes = consecutive i, same j loop -> broadcast loads.
__global__ void mask_kernel(const float* __restrict__ sx1, const float* __restrict__ sy1,
                            const float* __restrict__ sx2, const float* __restrict__ sy2,
                            const float* __restrict__ sarea, const int* __restrict__ scls,
                            const int* __restrict__ dV, unsigned long long* __restrict__ mask)
{
    int i  = blockIdx.x * blockDim.x + threadIdx.x;
    int jw = blockIdx.y;
    int V  = *dV;
    int W  = (V + 63) >> 6;
    if (i >= V || jw >= W) return;
    float x1 = sx1[i], y1 = sy1[i], x2 = sx2[i], y2 = sy2[i], ar = sarea[i];
    int ci = scls[i];
    unsigned long long bits = 0ull;
    int j0   = jw << 6;
    int jend = min(j0 + 64, V);
    for (int j = max(j0, i + 1); j < jend; ++j) {
        if (scls[j] != ci) continue;
        float xx1 = fmaxf(x1, sx1[j]);
        float yy1 = fmaxf(y1, sy1[j]);
        float xx2 = fminf(x2, sx2[j]);
        float yy2 = fminf(y2, sy2[j]);
        float w = fmaxf(xx2 - xx1, 0.0f);
        float h = fmaxf(yy2 - yy1, 0.0f);
        float inter = w * h;
        float uni   = ar + sarea[j] - inter;
        float iou   = inter / fmaxf(uni, 1e-9f);
        if (iou > 0.5f) bits |= (1ull << (j - j0));
    }
    mask[(size_t)i * W + jw] = bits;
}

// Sequential greedy pass: single wave, remv bitmask in LDS.
__global__ void __launch_bounds__(64) nms_seq_kernel(const unsigned long long* __restrict__ mask,
                                                     const int* __restrict__ dV,
                                                     int* __restrict__ keep)
{
    __shared__ unsigned long long remv[MAXW];
    __shared__ int kflag;
    int tid = threadIdx.x;
    int V = *dV;
    int W = (V + 63) >> 6;
    for (int w = tid; w < MAXW; w += 64) remv[w] = 0ull;
    __syncthreads();
    for (int i = 0; i < V; ++i) {
        if (tid == 0) {
            int sup = (int)((remv[i >> 6] >> (i & 63)) & 1ull);
            kflag = sup ^ 1;
            keep[i] = sup ^ 1;
        }
        __syncthreads();
        if (kflag) {
            const unsigned long long* row = mask + (size_t)i * W;
            for (int w = tid; w < W; w += 64) remv[w] |= row[w];
        }
        __syncthreads();
    }
}

// Emit kept rows; everything else already zeroed by memset.
__global__ void out_kernel(const float* __restrict__ box, const float* __restrict__ conf,
                           const int* __restrict__ cls, const int* __restrict__ order,
                           const int* __restrict__ keep, const int* __restrict__ dV,
                           float* __restrict__ out)
{
    int r = blockIdx.x * blockDim.x + threadIdx.x;
    if (r >= N_TOT) return;
    int V = *dV;
    if (r < V && keep[r]) {
        int i = order[r];
        out[r*6+0] = box[i*4+0];
        out[r*6+1] = box[i*4+1];
        out[r*6+2] = box[i*4+2];
        out[r*6+3] = box[i*4+3];
        out[r*6+4] = conf[i];
        out[r*6+5] = (float)cls[i];
    }
}

extern "C" void kernel_launch(void* const* d_in, const int* in_sizes, int n_in,
                              void* d_out, int out_size, void* d_ws, size_t ws_size,
                              hipStream_t stream) {
    const float* p0 = (const float*)d_in[0];
    const float* p1 = (const float*)d_in[1];
    const float* p2 = (const float*)d_in[2];
    float* out = (float*)d_out;
    char* ws = (char*)d_ws;
    const int N = N_TOT;

    float* box   = (float*)ws;          // 4N
    float* conf  = box + 4*N;           // N
    float* score = conf + N;            // N
    float* sx1   = score + N;           // N
    float* sy1   = sx1 + N;             // N
    float* sx2   = sy1 + N;             // N
    float* sy2   = sx2 + N;             // N
    float* sarea = sy2 + N;             // N
    int* cls   = (int*)(sarea + N);     // N
    int* order = cls + N;               // N
    int* keep  = order + N;             // N
    int* scls  = keep + N;              // N
    int* dV    = scls + N;              // 1 (+pad)
    uintptr_t maddr = ((uintptr_t)(dV + 2) + 7) & ~(uintptr_t)7;
    unsigned long long* mask = (unsigned long long*)maddr;  // worst case 14.2 MB, last

    hipMemsetAsync(d_out, 0, (size_t)out_size * sizeof(float), stream);
    hipMemsetAsync(dV, 0, sizeof(int), stream);

    const int NB = (N_TOT + 255) / 256;   // 42
    decode_kernel<<<NB, 256, 0, stream>>>(p0, p1, p2, box, conf, score, cls, dV);
    rank_kernel<<<NB, 256, 0, stream>>>(score, order);
    gather_kernel<<<NB, 256, 0, stream>>>(box, cls, order, dV, sx1, sy1, sx2, sy2, sarea, scls);
    mask_kernel<<<dim3(NB, MAXW), 256, 0, stream>>>(sx1, sy1, sx2, sy2, sarea, scls, dV, mask);
    nms_seq_kernel<<<1, 64, 0, stream>>>(mask, dV, keep);
    out_kernel<<<NB, 256, 0, stream>>>(box, conf, cls, order, keep, dV, out);
}

// Round 2
// 654.909 us; speedup vs baseline: 5.9171x; 5.9171x over previous
//
#include <hip/hip_runtime.h>
#include <stdint.h>

#define N_TOT 10647
#define MAXW  167   // ceil(10647/64)

typedef unsigned long long ull;

// YOLOv3 COCO anchors, grouped by head: [0..2]=13x13, [3..5]=26x26, [6..8]=52x52
__constant__ float c_aw[9] = {116.f,156.f,373.f, 30.f,62.f,59.f, 10.f,16.f,33.f};
__constant__ float c_ah[9] = { 90.f,198.f,326.f, 61.f,45.f,119.f, 13.f,30.f,23.f};

__device__ __forceinline__ float sigmoidf_(float x) { return 1.0f / (1.0f + expf(-x)); }

// One thread per box: decode (cx,cy,w,h), conf, argmax class, validity.
__global__ void decode_kernel(const float* __restrict__ p0,
                              const float* __restrict__ p1,
                              const float* __restrict__ p2,
                              float* __restrict__ box, float* __restrict__ conf,
                              float* __restrict__ score, int* __restrict__ cls,
                              int* __restrict__ dV)
{
    int n = blockIdx.x * blockDim.x + threadIdx.x;
    if (n >= N_TOT) return;
    const float* p; int H, base, lvl; float stride;
    if (n < 507)       { p = p0; H = 13; base = 0;    stride = 32.f; lvl = 0; }
    else if (n < 2535) { p = p1; H = 26; base = 507;  stride = 16.f; lvl = 1; }
    else               { p = p2; H = 52; base = 2535; stride = 8.f;  lvl = 2; }
    int m   = n - base;
    int HW  = H * H;
    int a   = m / HW;
    int rem = m - a * HW;
    int gy  = rem / H;
    int gx  = rem - gy * H;
    const float* q = p + (size_t)(a * 85) * HW + rem;
    float tx = q[0];
    float ty = q[(size_t)HW];
    float tw = q[(size_t)2*HW];
    float th = q[(size_t)3*HW];
    float tc = q[(size_t)4*HW];
    // argmax over 80 class logits (first max wins, like jnp.argmax)
    float best = q[(size_t)5*HW]; int bi = 0;
    for (int c = 1; c < 80; ++c) {
        float v = q[(size_t)(5+c)*HW];
        if (v > best) { best = v; bi = c; }
    }
    float cx = (sigmoidf_(tx) + (float)gx) * stride;
    float cy = (sigmoidf_(ty) + (float)gy) * stride;
    // exp(t)*(anchor/stride)*stride == exp(t)*anchor exactly (stride is a power of 2)
    float bw = expf(tw) * c_aw[lvl*3 + a];
    float bh = expf(th) * c_ah[lvl*3 + a];
    float cf = sigmoidf_(tc);
    box[n*4+0] = cx; box[n*4+1] = cy; box[n*4+2] = bw; box[n*4+3] = bh;
    conf[n] = cf;
    cls[n]  = bi;
    bool valid = (cf >= 0.5f);
    score[n] = valid ? cf : -1.0f;
    if (valid) atomicAdd(dV, 1);
}

// Stable descending rank among valid boxes via LDS-tiled compares; order[rank]=i.
__global__ void rank_kernel(const float* __restrict__ score, int* __restrict__ order)
{
    __shared__ float tile[256];
    int tid = threadIdx.x;
    int i = blockIdx.x * 256 + tid;
    float si = (i < N_TOT) ? score[i] : -2.0f;
    bool act = (si >= 0.0f);   // invalid boxes land past V; their rows stay zero
    int r = 0;
    for (int base = 0; base < N_TOT; base += 256) {
        int jj = base + tid;
        tile[tid] = (jj < N_TOT) ? score[jj] : -2.0f;  // sentinel < all scores
        __syncthreads();
        if (act) {
            int lim = min(256, N_TOT - base);
            if (lim == 256) {
                #pragma unroll 8
                for (int t = 0; t < 256; ++t) {
                    float sj = tile[t];
                    r += (sj > si || (sj == si && (base + t) < i)) ? 1 : 0;
                }
            } else {
                for (int t = 0; t < lim; ++t) {
                    float sj = tile[t];
                    r += (sj > si || (sj == si && (base + t) < i)) ? 1 : 0;
                }
            }
        }
        __syncthreads();
    }
    if (act) order[r] = i;
}

// Gather sorted corner/area/class arrays for the IoU pass.
__global__ void gather_kernel(const float* __restrict__ box, const int* __restrict__ cls,
                              const int* __restrict__ order, const int* __restrict__ dV,
                              float* __restrict__ sx1, float* __restrict__ sy1,
                              float* __restrict__ sx2, float* __restrict__ sy2,
                              float* __restrict__ sarea, int* __restrict__ scls)
{
    int r = blockIdx.x * blockDim.x + threadIdx.x;
    int V = *dV;
    if (r >= V) return;
    int i = order[r];
    float cx = box[i*4+0], cy = box[i*4+1], w = box[i*4+2], h = box[i*4+3];
    float hw = w * 0.5f, hh = h * 0.5f;
    sx1[r] = cx - hw; sy1[r] = cy - hh;
    sx2[r] = cx + hw; sy2[r] = cy + hh;
    sarea[r] = w * h;
    scls[r]  = cls[i];
}

// Transposed suppressor bitmask: maskT[i][jw] bit b set iff j=jw*64+b < i,
// same class, IoU > 0.5. Only words jw <= i>>6 are written/read.
__global__ void maskT_kernel(const float* __restrict__ sx1, const float* __restrict__ sy1,
                             const float* __restrict__ sx2, const float* __restrict__ sy2,
                             const float* __restrict__ sarea, const int* __restrict__ scls,
                             const int* __restrict__ dV, ull* __restrict__ maskT)
{
    int i  = blockIdx.x * blockDim.x + threadIdx.x;
    int jw = blockIdx.y;
    int V  = *dV;
    int W  = (V + 63) >> 6;
    if (i >= V) return;
    if (jw > (i >> 6)) return;
    float x1 = sx1[i], y1 = sy1[i], x2 = sx2[i], y2 = sy2[i], ar = sarea[i];
    int ci = scls[i];
    ull bits = 0ull;
    int j0   = jw << 6;
    int jend = min(j0 + 64, i);
    for (int j = j0; j < jend; ++j) {
        if (scls[j] != ci) continue;
        float xx1 = fmaxf(x1, sx1[j]);
        float yy1 = fmaxf(y1, sy1[j]);
        float xx2 = fminf(x2, sx2[j]);
        float yy2 = fminf(y2, sy2[j]);
        float w = fmaxf(xx2 - xx1, 0.0f);
        float h = fmaxf(yy2 - yy1, 0.0f);
        float inter = w * h;
        float uni   = ar + sarea[j] - inter;
        float iou   = inter / fmaxf(uni, 1e-9f);
        if (iou > 0.5f) bits |= (1ull << (j - j0));
    }
    maskT[(size_t)i * W + jw] = bits;
}

// Block-Jacobi fixpoint for greedy NMS. Group g = boxes [g*64,(g+1)*64).
// Per round: external suppressors from previous-round keep bits (Jacobi),
// internal 64-box chain resolved exactly in-register (ballot + shfl).
// Group g is exact after round g+1 => guaranteed convergence in <= W+1 rounds;
// rare suppressions on this data => ~2-3 rounds. Unique fixpoint == greedy NMS.
__global__ void __launch_bounds__(1024)
nms_fix_kernel(const ull* __restrict__ maskT, const int* __restrict__ dV,
               int* __restrict__ keep)
{
    __shared__ ull bufA[MAXW], bufB[MAXW];
    __shared__ int changed;
    int tid  = threadIdx.x;
    int lane = tid & 63;
    int wave = tid >> 6;            // 16 waves
    int V = *dV;
    int W = (V + 63) >> 6;
    if (W == 0) return;
    for (int w = tid; w < W; w += 1024) {
        int rem = V - (w << 6);
        bufA[w] = (rem >= 64) ? ~0ull : ((1ull << rem) - 1ull);
    }
    __syncthreads();
    ull* cur = bufA;
    ull* nxt = bufB;
    for (int round = 0; round < MAXW + 2; ++round) {
        if (tid == 0) changed = 0;
        __syncthreads();
        for (int g = wave; g < W; g += 16) {
            int i = (g << 6) + lane;
            bool inb = (i < V);
            const ull* row = maskT + (size_t)i * W;
            ull ext = 0ull;
            ull rowg = 0ull;
            if (inb) {
                for (int w = 0; w < g; ++w) ext |= (row[w] & cur[w]);
                rowg = row[g];
            }
            bool cand = inb && (ext == 0ull);
            ull cb = __ballot(cand);
            // serial intra-group greedy resolve (uniform across lanes)
            ull kept = 0ull;
            for (int b = 0; b < 64; ++b) {
                ull rb = __shfl(rowg, b);
                ull kb = ((cb >> b) & 1ull) & ((rb & kept) ? 0ull : 1ull);
                kept |= kb << b;
            }
            if (lane == 0) {
                nxt[g] = kept;
                if (kept != cur[g]) changed = 1;
            }
        }
        __syncthreads();
        int ch = changed;
        __syncthreads();   // all must read `changed` before next round resets it
        ull* t = cur; cur = nxt; nxt = t;
        if (!ch) break;
    }
    for (int g = wave; g < W; g += 16) {
        int i = (g << 6) + lane;
        if (i < V) keep[i] = (int)((cur[g] >> lane) & 1ull);
    }
}

// Emit kept rows; everything else already zeroed by memset.
__global__ void out_kernel(const float* __restrict__ box, const float* __restrict__ conf,
                           const int* __restrict__ cls, const int* __restrict__ order,
                           const int* __restrict__ keep, const int* __restrict__ dV,
                           float* __restrict__ out)
{
    int r = blockIdx.x * blockDim.x + threadIdx.x;
    if (r >= N_TOT) return;
    int V = *dV;
    if (r < V && keep[r]) {
        int i = order[r];
        out[r*6+0] = box[i*4+0];
        out[r*6+1] = box[i*4+1];
        out[r*6+2] = box[i*4+2];
        out[r*6+3] = box[i*4+3];
        out[r*6+4] = conf[i];
        out[r*6+5] = (float)cls[i];
    }
}

extern "C" void kernel_launch(void* const* d_in, const int* in_sizes, int n_in,
                              void* d_out, int out_size, void* d_ws, size_t ws_size,
                              hipStream_t stream) {
    const float* p0 = (const float*)d_in[0];
    const float* p1 = (const float*)d_in[1];
    const float* p2 = (const float*)d_in[2];
    float* out = (float*)d_out;
    char* ws = (char*)d_ws;
    const int N = N_TOT;

    float* box   = (float*)ws;          // 4N
    float* conf  = box + 4*N;           // N
    float* score = conf + N;            // N
    float* sx1   = score + N;           // N
    float* sy1   = sx1 + N;             // N
    float* sx2   = sy1 + N;             // N
    float* sy2   = sx2 + N;             // N
    float* sarea = sy2 + N;             // N
    int* cls   = (int*)(sarea + N);     // N
    int* order = cls + N;               // N
    int* keep  = order + N;             // N
    int* scls  = keep + N;              // N
    int* dV    = scls + N;              // 1 (+pad)
    uintptr_t maddr = ((uintptr_t)(dV + 2) + 7) & ~(uintptr_t)7;
    ull* maskT = (ull*)maddr;           // worst case 14.2 MB, last in ws

    hipMemsetAsync(d_out, 0, (size_t)out_size * sizeof(float), stream);
    hipMemsetAsync(dV, 0, sizeof(int), stream);

    const int NB = (N_TOT + 255) / 256;   // 42
    decode_kernel<<<NB, 256, 0, stream>>>(p0, p1, p2, box, conf, score, cls, dV);
    rank_kernel<<<NB, 256, 0, stream>>>(score, order);
    gather_kernel<<<NB, 256, 0, stream>>>(box, cls, order, dV, sx1, sy1, sx2, sy2, sarea, scls);
    maskT_kernel<<<dim3(NB, MAXW), 256, 0, stream>>>(sx1, sy1, sx2, sy2, sarea, scls, dV, maskT);
    nms_fix_kernel<<<1, 1024, 0, stream>>>(maskT, dV, keep);
    out_kernel<<<NB, 256, 0, stream>>>(box, conf, cls, order, keep, dV, out);
}

// Round 3
// 256.736 us; speedup vs baseline: 15.0940x; 2.5509x over previous
//
#include <hip/hip_runtime.h>
#include <stdint.h>

#define N_TOT 10647
#define N_PAD 10688   // N_TOT rounded up to 64
#define MAXW  167     // ceil(10647/64)
#define RANK_SLICE 2662  // ceil(10647/4)

typedef unsigned long long ull;

// YOLOv3 COCO anchors, grouped by head: [0..2]=13x13, [3..5]=26x26, [6..8]=52x52
__constant__ float c_aw[9] = {116.f,156.f,373.f, 30.f,62.f,59.f, 10.f,16.f,33.f};
__constant__ float c_ah[9] = { 90.f,198.f,326.f, 61.f,45.f,119.f, 13.f,30.f,23.f};

__device__ __forceinline__ float sigmoidf_(float x) { return 1.0f / (1.0f + expf(-x)); }

// One thread per box: decode (cx,cy,w,h), conf, argmax class, validity.
__global__ void decode_kernel(const float* __restrict__ p0,
                              const float* __restrict__ p1,
                              const float* __restrict__ p2,
                              float* __restrict__ box, float* __restrict__ conf,
                              float* __restrict__ score, int* __restrict__ cls,
                              int* __restrict__ dV)
{
    int n = blockIdx.x * blockDim.x + threadIdx.x;
    if (n >= N_TOT) return;
    const float* p; int H, base, lvl; float stride;
    if (n < 507)       { p = p0; H = 13; base = 0;    stride = 32.f; lvl = 0; }
    else if (n < 2535) { p = p1; H = 26; base = 507;  stride = 16.f; lvl = 1; }
    else               { p = p2; H = 52; base = 2535; stride = 8.f;  lvl = 2; }
    int m   = n - base;
    int HW  = H * H;
    int a   = m / HW;
    int rem = m - a * HW;
    int gy  = rem / H;
    int gx  = rem - gy * H;
    const float* q = p + (size_t)(a * 85) * HW + rem;
    float tx = q[0];
    float ty = q[(size_t)HW];
    float tw = q[(size_t)2*HW];
    float th = q[(size_t)3*HW];
    float tc = q[(size_t)4*HW];
    // argmax over 80 class logits (first max wins, like jnp.argmax)
    float best = q[(size_t)5*HW]; int bi = 0;
    for (int c = 1; c < 80; ++c) {
        float v = q[(size_t)(5+c)*HW];
        if (v > best) { best = v; bi = c; }
    }
    float cx = (sigmoidf_(tx) + (float)gx) * stride;
    float cy = (sigmoidf_(ty) + (float)gy) * stride;
    // exp(t)*(anchor/stride)*stride == exp(t)*anchor exactly (stride is a power of 2)
    float bw = expf(tw) * c_aw[lvl*3 + a];
    float bh = expf(th) * c_ah[lvl*3 + a];
    float cf = sigmoidf_(tc);
    box[n*4+0] = cx; box[n*4+1] = cy; box[n*4+2] = bw; box[n*4+3] = bh;
    conf[n] = cf;
    cls[n]  = bi;
    bool valid = (cf >= 0.5f);
    score[n] = valid ? cf : -1.0f;
    if (valid) atomicAdd(dV, 1);
}

// Partial stable-descending rank: block (bx,by) counts slice by for the 256
// boxes of tile bx. rank4[by*N + i] = partial count. No atomics.
__global__ void rank_partial_kernel(const float* __restrict__ score,
                                    int* __restrict__ rank4)
{
    __shared__ float tile[256];
    int tid = threadIdx.x;
    int i   = blockIdx.x * 256 + tid;
    int sl  = blockIdx.y;
    int jbeg = sl * RANK_SLICE;
    int jend = min(jbeg + RANK_SLICE, N_TOT);
    float si = (i < N_TOT) ? score[i] : -2.0f;
    bool act = (si >= 0.0f);
    int r = 0;
    for (int base = jbeg; base < jend; base += 256) {
        int jj = base + tid;
        tile[tid] = (jj < jend) ? score[jj] : -2.0f;
        __syncthreads();
        int lim = min(256, jend - base);
        if (act) {
            #pragma unroll 8
            for (int t = 0; t < lim; ++t) {
                float sj = tile[t];
                r += (sj > si || (sj == si && (base + t) < i)) ? 1 : 0;
            }
        }
        __syncthreads();
    }
    if (i < N_TOT) rank4[(size_t)sl * N_TOT + i] = r;
}

// Sum partial ranks, scatter order[r]=i, and gather corner/area/class arrays.
__global__ void scatter_gather_kernel(const float* __restrict__ box,
                                      const int* __restrict__ cls,
                                      const float* __restrict__ score,
                                      const int* __restrict__ rank4,
                                      int* __restrict__ order,
                                      float* __restrict__ sx1, float* __restrict__ sy1,
                                      float* __restrict__ sx2, float* __restrict__ sy2,
                                      float* __restrict__ sarea, int* __restrict__ scls)
{
    int i = blockIdx.x * blockDim.x + threadIdx.x;
    if (i >= N_TOT) return;
    if (score[i] < 0.0f) return;
    int r = rank4[i] + rank4[N_TOT + i] + rank4[2*N_TOT + i] + rank4[3*N_TOT + i];
    order[r] = i;
    float cx = box[i*4+0], cy = box[i*4+1], w = box[i*4+2], h = box[i*4+3];
    float hw = w * 0.5f, hh = h * 0.5f;
    sx1[r] = cx - hw; sy1[r] = cy - hh;
    sx2[r] = cx + hw; sy2[r] = cy + hh;
    sarea[r] = w * h;
    scls[r]  = cls[i];
}

// Transposed (word-major) suppressor bitmask: maskTt[jw*N_PAD + i] bit b set
// iff j=jw*64+b < i, same class, IoU > 0.5. Consecutive i => coalesced writes.
__global__ void maskT_kernel(const float* __restrict__ sx1, const float* __restrict__ sy1,
                             const float* __restrict__ sx2, const float* __restrict__ sy2,
                             const float* __restrict__ sarea, const int* __restrict__ scls,
                             const int* __restrict__ dV, ull* __restrict__ maskTt)
{
    int i  = blockIdx.x * blockDim.x + threadIdx.x;
    int jw = blockIdx.y;
    int V  = *dV;
    if (i >= V) return;
    if (jw > (i >> 6)) return;
    float x1 = sx1[i], y1 = sy1[i], x2 = sx2[i], y2 = sy2[i], ar = sarea[i];
    int ci = scls[i];
    ull bits = 0ull;
    int j0   = jw << 6;
    int jend = min(j0 + 64, i);
    for (int j = j0; j < jend; ++j) {
        if (scls[j] != ci) continue;
        float xx1 = fmaxf(x1, sx1[j]);
        float yy1 = fmaxf(y1, sy1[j]);
        float xx2 = fminf(x2, sx2[j]);
        float yy2 = fminf(y2, sy2[j]);
        float w = fmaxf(xx2 - xx1, 0.0f);
        float h = fmaxf(yy2 - yy1, 0.0f);
        float inter = w * h;
        float uni   = ar + sarea[j] - inter;
        float iou   = inter / fmaxf(uni, 1e-9f);
        if (iou > 0.5f) bits |= (1ull << (j - j0));
    }
    maskTt[(size_t)jw * N_PAD + i] = bits;
}

// Exact greedy NMS in ONE left-to-right sweep over 64-box groups.
// ext OR parallelized over 16 waves (coalesced word-major loads); intra-group
// resolve fast-pathed (ballot) unless a candidate-candidate edge exists.
__global__ void __launch_bounds__(1024)
nms_sweep_kernel(const ull* __restrict__ maskTt, const int* __restrict__ dV,
                 int* __restrict__ keep)
{
    __shared__ ull kw[MAXW];
    __shared__ ull ext_part[16][64];
    int tid  = threadIdx.x;
    int lane = tid & 63;
    int wave = tid >> 6;            // 16 waves
    int V = *dV;
    int W = (V + 63) >> 6;
    for (int g = 0; g < W; ++g) {
        int i = (g << 6) + lane;
        bool inb = (i < V);
        ull part = 0ull;
        for (int w = wave; w < g; w += 16) {
            ull m = inb ? maskTt[(size_t)w * N_PAD + i] : 0ull;
            part |= (m & kw[w]);
        }
        ext_part[wave][lane] = part;
        __syncthreads();
        if (wave == 0) {
            ull ext = 0ull;
            #pragma unroll
            for (int v = 0; v < 16; ++v) ext |= ext_part[v][lane];
            ull rowg = inb ? maskTt[(size_t)g * N_PAD + i] : 0ull;
            bool cand = inb && (ext == 0ull);
            ull cb = __ballot(cand);
            ull kept;
            ull conflict = __ballot(cand && ((rowg & cb) != 0ull));
            if (conflict == 0ull) {
                kept = cb;          // no candidate suppresses another candidate
            } else {
                kept = 0ull;        // rare: exact serial chain within the group
                for (int b = 0; b < 64; ++b) {
                    ull rb = __shfl(rowg, b);
                    ull kb = ((cb >> b) & 1ull) & ((rb & kept) ? 0ull : 1ull);
                    kept |= kb << b;
                }
            }
            if (lane == 0) kw[g] = kept;
        }
        __syncthreads();
    }
    for (int g = wave; g < W; g += 16) {
        int i = (g << 6) + lane;
        if (i < V) keep[i] = (int)((kw[g] >> lane) & 1ull);
    }
}

// Emit kept rows; everything else already zeroed by memset.
__global__ void out_kernel(const float* __restrict__ box, const float* __restrict__ conf,
                           const int* __restrict__ cls, const int* __restrict__ order,
                           const int* __restrict__ keep, const int* __restrict__ dV,
                           float* __restrict__ out)
{
    int r = blockIdx.x * blockDim.x + threadIdx.x;
    if (r >= N_TOT) return;
    int V = *dV;
    if (r < V && keep[r]) {
        int i = order[r];
        out[r*6+0] = box[i*4+0];
        out[r*6+1] = box[i*4+1];
        out[r*6+2] = box[i*4+2];
        out[r*6+3] = box[i*4+3];
        out[r*6+4] = conf[i];
        out[r*6+5] = (float)cls[i];
    }
}

extern "C" void kernel_launch(void* const* d_in, const int* in_sizes, int n_in,
                              void* d_out, int out_size, void* d_ws, size_t ws_size,
                              hipStream_t stream) {
    const float* p0 = (const float*)d_in[0];
    const float* p1 = (const float*)d_in[1];
    const float* p2 = (const float*)d_in[2];
    float* out = (float*)d_out;
    char* ws = (char*)d_ws;
    const int N = N_TOT;

    float* box   = (float*)ws;          // 4N
    float* conf  = box + 4*N;           // N
    float* score = conf + N;            // N
    float* sx1   = score + N;           // N
    float* sy1   = sx1 + N;             // N
    float* sx2   = sy1 + N;             // N
    float* sy2   = sx2 + N;             // N
    float* sarea = sy2 + N;             // N
    int* cls   = (int*)(sarea + N);     // N
    int* order = cls + N;               // N
    int* keep  = order + N;             // N
    int* scls  = keep + N;              // N
    int* dV    = scls + N;              // 1 (+pad)
    uintptr_t maddr = ((uintptr_t)(dV + 2) + 7) & ~(uintptr_t)7;
    ull* maskTt = (ull*)maddr;          // MAXW * N_PAD words = 14.28 MB, last in ws
    int* rank4  = (int*)maddr;          // 4N ints, overlays maskTt (dead before maskT writes)

    hipMemsetAsync(d_out, 0, (size_t)out_size * sizeof(float), stream);
    hipMemsetAsync(dV, 0, sizeof(int), stream);

    const int NB = (N_TOT + 255) / 256;   // 42
    decode_kernel<<<NB, 256, 0, stream>>>(p0, p1, p2, box, conf, score, cls, dV);
    rank_partial_kernel<<<dim3(NB, 4), 256, 0, stream>>>(score, rank4);
    scatter_gather_kernel<<<NB, 256, 0, stream>>>(box, cls, score, rank4, order,
                                                  sx1, sy1, sx2, sy2, sarea, scls);
    maskT_kernel<<<dim3(NB, MAXW), 256, 0, stream>>>(sx1, sy1, sx2, sy2, sarea, scls, dV, maskTt);
    nms_sweep_kernel<<<1, 1024, 0, stream>>>(maskTt, dV, keep);
    out_kernel<<<NB, 256, 0, stream>>>(box, conf, cls, order, keep, dV, out);
}

// Round 4
// 149.921 us; speedup vs baseline: 25.8482x; 1.7125x over previous
//
#include <hip/hip_runtime.h>
#include <stdint.h>

#define N_TOT 10647
#define MAXW  167     // ceil(10647/64)
#define RANK_SLICE 2662  // ceil(10647/4)
#define ECAP  (1 << 20)  // edge buffer cap (4 MB); expected E ~ 1e3-1e4

typedef unsigned long long ull;

// YOLOv3 COCO anchors, grouped by head: [0..2]=13x13, [3..5]=26x26, [6..8]=52x52
__constant__ float c_aw[9] = {116.f,156.f,373.f, 30.f,62.f,59.f, 10.f,16.f,33.f};
__constant__ float c_ah[9] = { 90.f,198.f,326.f, 61.f,45.f,119.f, 13.f,30.f,23.f};

__device__ __forceinline__ float sigmoidf_(float x) { return 1.0f / (1.0f + expf(-x)); }

// One thread per box: decode (cx,cy,w,h), conf, argmax class, validity.
__global__ void decode_kernel(const float* __restrict__ p0,
                              const float* __restrict__ p1,
                              const float* __restrict__ p2,
                              float* __restrict__ box, float* __restrict__ conf,
                              float* __restrict__ score, int* __restrict__ cls,
                              int* __restrict__ dV)
{
    int n = blockIdx.x * blockDim.x + threadIdx.x;
    if (n >= N_TOT) return;
    const float* p; int H, base, lvl; float stride;
    if (n < 507)       { p = p0; H = 13; base = 0;    stride = 32.f; lvl = 0; }
    else if (n < 2535) { p = p1; H = 26; base = 507;  stride = 16.f; lvl = 1; }
    else               { p = p2; H = 52; base = 2535; stride = 8.f;  lvl = 2; }
    int m   = n - base;
    int HW  = H * H;
    int a   = m / HW;
    int rem = m - a * HW;
    int gy  = rem / H;
    int gx  = rem - gy * H;
    const float* q = p + (size_t)(a * 85) * HW + rem;
    float tx = q[0];
    float ty = q[(size_t)HW];
    float tw = q[(size_t)2*HW];
    float th = q[(size_t)3*HW];
    float tc = q[(size_t)4*HW];
    // argmax over 80 class logits (first max wins, like jnp.argmax)
    float best = q[(size_t)5*HW]; int bi = 0;
    for (int c = 1; c < 80; ++c) {
        float v = q[(size_t)(5+c)*HW];
        if (v > best) { best = v; bi = c; }
    }
    float cx = (sigmoidf_(tx) + (float)gx) * stride;
    float cy = (sigmoidf_(ty) + (float)gy) * stride;
    // exp(t)*(anchor/stride)*stride == exp(t)*anchor exactly (stride is a power of 2)
    float bw = expf(tw) * c_aw[lvl*3 + a];
    float bh = expf(th) * c_ah[lvl*3 + a];
    float cf = sigmoidf_(tc);
    box[n*4+0] = cx; box[n*4+1] = cy; box[n*4+2] = bw; box[n*4+3] = bh;
    conf[n] = cf;
    cls[n]  = bi;
    bool valid = (cf >= 0.5f);
    score[n] = valid ? cf : -1.0f;
    if (valid) atomicAdd(dV, 1);
}

// Partial stable-descending rank: block (bx,by) counts slice by for the 256
// boxes of tile bx. rank4[by*N + i] = partial count. No atomics.
__global__ void rank_partial_kernel(const float* __restrict__ score,
                                    int* __restrict__ rank4)
{
    __shared__ float tile[256];
    int tid = threadIdx.x;
    int i   = blockIdx.x * 256 + tid;
    int sl  = blockIdx.y;
    int jbeg = sl * RANK_SLICE;
    int jend = min(jbeg + RANK_SLICE, N_TOT);
    float si = (i < N_TOT) ? score[i] : -2.0f;
    bool act = (si >= 0.0f);
    int r = 0;
    for (int base = jbeg; base < jend; base += 256) {
        int jj = base + tid;
        tile[tid] = (jj < jend) ? score[jj] : -2.0f;
        __syncthreads();
        int lim = min(256, jend - base);
        if (act) {
            #pragma unroll 8
            for (int t = 0; t < lim; ++t) {
                float sj = tile[t];
                r += (sj > si || (sj == si && (base + t) < i)) ? 1 : 0;
            }
        }
        __syncthreads();
    }
    if (i < N_TOT) rank4[(size_t)sl * N_TOT + i] = r;
}

// Sum partial ranks, scatter order[r]=i, and gather corner/area/class arrays.
__global__ void scatter_gather_kernel(const float* __restrict__ box,
                                      const int* __restrict__ cls,
                                      const float* __restrict__ score,
                                      const int* __restrict__ rank4,
                                      int* __restrict__ order,
                                      float* __restrict__ sx1, float* __restrict__ sy1,
                                      float* __restrict__ sx2, float* __restrict__ sy2,
                                      float* __restrict__ sarea, int* __restrict__ scls)
{
    int i = blockIdx.x * blockDim.x + threadIdx.x;
    if (i >= N_TOT) return;
    if (score[i] < 0.0f) return;
    int r = rank4[i] + rank4[N_TOT + i] + rank4[2*N_TOT + i] + rank4[3*N_TOT + i];
    order[r] = i;
    float cx = box[i*4+0], cy = box[i*4+1], w = box[i*4+2], h = box[i*4+3];
    float hw = w * 0.5f, hh = h * 0.5f;
    sx1[r] = cx - hw; sy1[r] = cy - hh;
    sx2[r] = cx + hw; sy2[r] = cy + hh;
    sarea[r] = w * h;
    scls[r]  = cls[i];
}

// Sparse suppression edges over the sorted valid prefix: for each pair j<i with
// same class and IoU>0.5, append packed (i<<16|j). Tiled 256x256, j staged in LDS.
__global__ void edge_kernel(const float* __restrict__ sx1, const float* __restrict__ sy1,
                            const float* __restrict__ sx2, const float* __restrict__ sy2,
                            const float* __restrict__ sarea, const int* __restrict__ scls,
                            const int* __restrict__ dV,
                            uint32_t* __restrict__ edges, int* __restrict__ ecnt)
{
    __shared__ float tx1[256], ty1[256], tx2[256], ty2[256], tar[256];
    __shared__ int   tcl[256];
    int bi = blockIdx.x, bj = blockIdx.y;
    if (bj > bi) return;
    int V = *dV;
    int j0 = bj << 8;
    if (j0 >= V) return;
    int tid = threadIdx.x;
    int jj = j0 + tid;
    if (jj < V) {
        tx1[tid] = sx1[jj]; ty1[tid] = sy1[jj];
        tx2[tid] = sx2[jj]; ty2[tid] = sy2[jj];
        tar[tid] = sarea[jj]; tcl[tid] = scls[jj];
    }
    __syncthreads();
    int i = (bi << 8) + tid;
    if (i >= V) return;
    float x1 = sx1[i], y1 = sy1[i], x2 = sx2[i], y2 = sy2[i], ar = sarea[i];
    int ci = scls[i];
    int jlim = min(min(256, V - j0), i - j0);   // j < i
    for (int t = 0; t < jlim; ++t) {
        if (tcl[t] != ci) continue;
        float xx1 = fmaxf(x1, tx1[t]);
        float yy1 = fmaxf(y1, ty1[t]);
        float xx2 = fminf(x2, tx2[t]);
        float yy2 = fminf(y2, ty2[t]);
        float w = fmaxf(xx2 - xx1, 0.0f);
        float h = fmaxf(yy2 - yy1, 0.0f);
        float inter = w * h;
        float uni   = ar + tar[t] - inter;
        float iou   = inter / fmaxf(uni, 1e-9f);
        if (iou > 0.5f) {
            int pos = atomicAdd(ecnt, 1);
            if (pos < ECAP) edges[pos] = ((uint32_t)i << 16) | (uint32_t)(j0 + t);
        }
    }
}

// Sparse Jacobi fixpoint for greedy NMS, keep bitmap in LDS.
// keep_new[i] = valid[i] & !OR_{edges (j,i)} keep_prev[j].
// A zero-change round is the unique fixpoint == greedy solution (induction over
// the index-ordered DAG); depth-d nodes are final after d+1 rounds, so the
// round cap V+2 guarantees exactness.
__global__ void __launch_bounds__(1024)
nms_sparse_kernel(const uint32_t* __restrict__ edges, const int* __restrict__ ecnt_p,
                  const int* __restrict__ dV, int* __restrict__ keep)
{
    __shared__ ull kA[MAXW], kB[MAXW], sup[MAXW];
    __shared__ int changed;
    int tid = threadIdx.x;
    int V = *dV;
    int W = (V + 63) >> 6;
    if (W == 0) return;
    int E = min(*ecnt_p, ECAP);
    for (int w = tid; w < W; w += 1024) {
        int rem = V - (w << 6);
        kA[w] = (rem >= 64) ? ~0ull : ((1ull << rem) - 1ull);
    }
    ull* cur = kA;
    ull* nxt = kB;
    __syncthreads();
    for (int round = 0; round <= V + 2; ++round) {
        for (int w = tid; w < W; w += 1024) sup[w] = 0ull;
        if (tid == 0) changed = 0;
        __syncthreads();
        for (int e = tid; e < E; e += 1024) {
            uint32_t pk = edges[e];
            int j = pk & 0xFFFF;
            int i = pk >> 16;
            if ((cur[j >> 6] >> (j & 63)) & 1ull)
                atomicOr(&sup[i >> 6], 1ull << (i & 63));
        }
        __syncthreads();
        for (int w = tid; w < W; w += 1024) {
            int rem = V - (w << 6);
            ull valid = (rem >= 64) ? ~0ull : ((1ull << rem) - 1ull);
            ull nk = valid & ~sup[w];
            nxt[w] = nk;
            if (nk != cur[w]) changed = 1;
        }
        __syncthreads();
        int ch = changed;
        __syncthreads();   // everyone reads `changed` before next round resets it
        ull* t = cur; cur = nxt; nxt = t;
        if (!ch) break;
    }
    for (int w = tid; w < W; w += 1024) {
        ull kwv = cur[w];
        int base = w << 6;
        for (int b = 0; b < 64; ++b) {
            int i = base + b;
            if (i < V) keep[i] = (int)((kwv >> b) & 1ull);
        }
    }
}

// Emit kept rows; everything else already zeroed by memset.
__global__ void out_kernel(const float* __restrict__ box, const float* __restrict__ conf,
                           const int* __restrict__ cls, const int* __restrict__ order,
                           const int* __restrict__ keep, const int* __restrict__ dV,
                           float* __restrict__ out)
{
    int r = blockIdx.x * blockDim.x + threadIdx.x;
    if (r >= N_TOT) return;
    int V = *dV;
    if (r < V && keep[r]) {
        int i = order[r];
        out[r*6+0] = box[i*4+0];
        out[r*6+1] = box[i*4+1];
        out[r*6+2] = box[i*4+2];
        out[r*6+3] = box[i*4+3];
        out[r*6+4] = conf[i];
        out[r*6+5] = (float)cls[i];
    }
}

extern "C" void kernel_launch(void* const* d_in, const int* in_sizes, int n_in,
                              void* d_out, int out_size, void* d_ws, size_t ws_size,
                              hipStream_t stream) {
    const float* p0 = (const float*)d_in[0];
    const float* p1 = (const float*)d_in[1];
    const float* p2 = (const float*)d_in[2];
    float* out = (float*)d_out;
    char* ws = (char*)d_ws;
    const int N = N_TOT;

    float* box   = (float*)ws;          // 4N
    float* conf  = box + 4*N;           // N
    float* score = conf + N;            // N
    float* sx1   = score + N;           // N
    float* sy1   = sx1 + N;             // N
    float* sx2   = sy1 + N;             // N
    float* sy2   = sx2 + N;             // N
    float* sarea = sy2 + N;             // N
    int* cls   = (int*)(sarea + N);     // N
    int* order = cls + N;               // N
    int* keep  = order + N;             // N
    int* scls  = keep + N;              // N
    int* rank4 = scls + N;              // 4N
    int* dV    = rank4 + 4*N;           // 1
    int* ecnt  = dV + 1;                // 1
    uintptr_t eaddr = ((uintptr_t)(ecnt + 1) + 15) & ~(uintptr_t)15;
    uint32_t* edges = (uint32_t*)eaddr; // ECAP u32 = 4 MB, last in ws

    hipMemsetAsync(d_out, 0, (size_t)out_size * sizeof(float), stream);
    hipMemsetAsync(dV, 0, 2 * sizeof(int), stream);   // dV and ecnt are adjacent

    const int NB = (N_TOT + 255) / 256;   // 42
    decode_kernel<<<NB, 256, 0, stream>>>(p0, p1, p2, box, conf, score, cls, dV);
    rank_partial_kernel<<<dim3(NB, 4), 256, 0, stream>>>(score, rank4);
    scatter_gather_kernel<<<NB, 256, 0, stream>>>(box, cls, score, rank4, order,
                                                  sx1, sy1, sx2, sy2, sarea, scls);
    edge_kernel<<<dim3(NB, NB), 256, 0, stream>>>(sx1, sy1, sx2, sy2, sarea, scls,
                                                  dV, edges, ecnt);
    nms_sparse_kernel<<<1, 1024, 0, stream>>>(edges, ecnt, dV, keep);
    out_kernel<<<NB, 256, 0, stream>>>(box, conf, cls, order, keep, dV, out);
}

// Round 5
// 87.640 us; speedup vs baseline: 44.2172x; 1.7106x over previous
//
#include <hip/hip_runtime.h>
#include <stdint.h>

#define N_TOT 10647
#define MAXW  167        // ceil(10647/64)
#define NB    42         // ceil(10647/256)
#define NBD   167        // ceil(10647/64) decode blocks
#define ECAP  (1 << 20)  // edge buffer cap (4 MB); expected E ~ 1e3-1e4

typedef unsigned long long ull;

// YOLOv3 COCO anchors, grouped by head: [0..2]=13x13, [3..5]=26x26, [6..8]=52x52
__constant__ float c_aw[9] = {116.f,156.f,373.f, 30.f,62.f,59.f, 10.f,16.f,33.f};
__constant__ float c_ah[9] = { 90.f,198.f,326.f, 61.f,45.f,119.f, 13.f,30.f,23.f};

__device__ __forceinline__ float sigmoidf_(float x) { return 1.0f / (1.0f + expf(-x)); }

// 4 threads per box: sub s (=tid>>6) scans classes [20s,20s+20); lane (=tid&63)
// picks the box. Strict '>' everywhere preserves jnp.argmax first-max-wins.
__global__ void __launch_bounds__(256)
decode_kernel(const float* __restrict__ p0, const float* __restrict__ p1,
              const float* __restrict__ p2,
              float* __restrict__ box, float* __restrict__ conf,
              float* __restrict__ score, int* __restrict__ cls,
              int* __restrict__ dV)
{
    __shared__ float sbest[4][64];
    __shared__ int   sbi[4][64];
    int sub  = threadIdx.x >> 6;
    int lane = threadIdx.x & 63;
    int n = blockIdx.x * 64 + lane;
    bool inb = (n < N_TOT);
    const float* p; int H, base, lvl; float stride;
    int nn = inb ? n : 0;
    if (nn < 507)       { p = p0; H = 13; base = 0;    stride = 32.f; lvl = 0; }
    else if (nn < 2535) { p = p1; H = 26; base = 507;  stride = 16.f; lvl = 1; }
    else                { p = p2; H = 52; base = 2535; stride = 8.f;  lvl = 2; }
    int m   = nn - base;
    int HW  = H * H;
    int a   = m / HW;
    int rem = m - a * HW;
    const float* q = p + (size_t)(a * 85) * HW + rem;
    float best = -3.4e38f; int bi = 20 * sub;
    if (inb) {
        int c0 = 20 * sub;
        #pragma unroll 5
        for (int c = c0; c < c0 + 20; ++c) {
            float v = q[(size_t)(5 + c) * HW];
            if (v > best) { best = v; bi = c; }
        }
    }
    sbest[sub][lane] = best;
    sbi[sub][lane]   = bi;
    __syncthreads();
    if (sub == 0 && inb) {
        float b0 = sbest[0][lane]; int i0 = sbi[0][lane];
        #pragma unroll
        for (int s = 1; s < 4; ++s) {
            float bs = sbest[s][lane];
            if (bs > b0) { b0 = bs; i0 = sbi[s][lane]; }
        }
        int gy = rem / H;
        int gx = rem - gy * H;
        float tx = q[0];
        float ty = q[(size_t)HW];
        float tw = q[(size_t)2*HW];
        float th = q[(size_t)3*HW];
        float tc = q[(size_t)4*HW];
        float cx = (sigmoidf_(tx) + (float)gx) * stride;
        float cy = (sigmoidf_(ty) + (float)gy) * stride;
        // exp(t)*(anchor/stride)*stride == exp(t)*anchor exactly (stride pow2)
        float bw = expf(tw) * c_aw[lvl*3 + a];
        float bh = expf(th) * c_ah[lvl*3 + a];
        float cf = sigmoidf_(tc);
        box[n*4+0] = cx; box[n*4+1] = cy; box[n*4+2] = bw; box[n*4+3] = bh;
        conf[n] = cf;
        cls[n]  = i0;
        bool valid = (cf >= 0.5f);
        score[n] = valid ? cf : -1.0f;
        if (valid) atomicAdd(dV, 1);
    }
}

// Partial stable-descending rank: block (bx,by) compares i-tile bx against
// j-tile by (staged in LDS). rank42[by*N + i] = partial count. No atomics.
__global__ void __launch_bounds__(256)
rank_partial_kernel(const float* __restrict__ score, int* __restrict__ rank42)
{
    __shared__ float tile[256];
    int tid = threadIdx.x;
    int i   = blockIdx.x * 256 + tid;
    int j0  = blockIdx.y * 256;
    int jj  = j0 + tid;
    tile[tid] = (jj < N_TOT) ? score[jj] : -2.0f;   // sentinel < all scores
    __syncthreads();
    float si = (i < N_TOT) ? score[i] : -2.0f;
    if (i >= N_TOT || si < 0.0f) return;            // invalid i: partial unused
    int r = 0;
    #pragma unroll 8
    for (int t = 0; t < 256; ++t) {
        float sj = tile[t];
        r += (sj > si || (sj == si && (j0 + t) < i)) ? 1 : 0;
    }
    rank42[(size_t)blockIdx.y * N_TOT + i] = r;
}

// Sum partial ranks, scatter order[r]=i, and gather corner/area/class arrays.
__global__ void __launch_bounds__(256)
scatter_gather_kernel(const float* __restrict__ box, const int* __restrict__ cls,
                      const float* __restrict__ score, const int* __restrict__ rank42,
                      int* __restrict__ order,
                      float* __restrict__ sx1, float* __restrict__ sy1,
                      float* __restrict__ sx2, float* __restrict__ sy2,
                      float* __restrict__ sarea, int* __restrict__ scls)
{
    int i = blockIdx.x * blockDim.x + threadIdx.x;
    if (i >= N_TOT) return;
    if (score[i] < 0.0f) return;
    int r = 0;
    #pragma unroll 6
    for (int s = 0; s < NB; ++s) r += rank42[(size_t)s * N_TOT + i];
    order[r] = i;
    float cx = box[i*4+0], cy = box[i*4+1], w = box[i*4+2], h = box[i*4+3];
    float hw = w * 0.5f, hh = h * 0.5f;
    sx1[r] = cx - hw; sy1[r] = cy - hh;
    sx2[r] = cx + hw; sy2[r] = cy + hh;
    sarea[r] = w * h;
    scls[r]  = cls[i];
}

// Sparse suppression edges over the sorted valid prefix: for each pair j<i with
// same class and IoU>0.5, append packed (i<<16|j). Tiled 256x256, j staged in LDS.
__global__ void __launch_bounds__(256)
edge_kernel(const float* __restrict__ sx1, const float* __restrict__ sy1,
            const float* __restrict__ sx2, const float* __restrict__ sy2,
            const float* __restrict__ sarea, const int* __restrict__ scls,
            const int* __restrict__ dV,
            uint32_t* __restrict__ edges, int* __restrict__ ecnt)
{
    __shared__ float tx1[256], ty1[256], tx2[256], ty2[256], tar[256];
    __shared__ int   tcl[256];
    int bi = blockIdx.x, bj = blockIdx.y;
    if (bj > bi) return;
    int V = *dV;
    int j0 = bj << 8;
    if (j0 >= V) return;
    int tid = threadIdx.x;
    int jj = j0 + tid;
    if (jj < V) {
        tx1[tid] = sx1[jj]; ty1[tid] = sy1[jj];
        tx2[tid] = sx2[jj]; ty2[tid] = sy2[jj];
        tar[tid] = sarea[jj]; tcl[tid] = scls[jj];
    }
    __syncthreads();
    int i = (bi << 8) + tid;
    if (i >= V) return;
    float x1 = sx1[i], y1 = sy1[i], x2 = sx2[i], y2 = sy2[i], ar = sarea[i];
    int ci = scls[i];
    int jlim = min(min(256, V - j0), i - j0);   // j < i
    for (int t = 0; t < jlim; ++t) {
        if (tcl[t] != ci) continue;
        float xx1 = fmaxf(x1, tx1[t]);
        float yy1 = fmaxf(y1, ty1[t]);
        float xx2 = fminf(x2, tx2[t]);
        float yy2 = fminf(y2, ty2[t]);
        float w = fmaxf(xx2 - xx1, 0.0f);
        float h = fmaxf(yy2 - yy1, 0.0f);
        float inter = w * h;
        float uni   = ar + tar[t] - inter;
        float iou   = inter / fmaxf(uni, 1e-9f);
        if (iou > 0.5f) {
            int pos = atomicAdd(ecnt, 1);
            if (pos < ECAP) edges[pos] = ((uint32_t)i << 16) | (uint32_t)(j0 + t);
        }
    }
}

// Sparse Jacobi fixpoint for greedy NMS, keep bitmap in LDS.
// keep_new[i] = valid[i] & !OR_{edges (j,i)} keep_prev[j].
// Zero-change round == unique fixpoint == greedy solution (induction over the
// index-ordered DAG); depth-d nodes final after d+1 rounds; cap V+2 => exact.
__global__ void __launch_bounds__(1024)
nms_sparse_kernel(const uint32_t* __restrict__ edges, const int* __restrict__ ecnt_p,
                  const int* __restrict__ dV, int* __restrict__ keep)
{
    __shared__ ull kA[MAXW], kB[MAXW], sup[MAXW];
    __shared__ int changed;
    int tid = threadIdx.x;
    int V = *dV;
    int W = (V + 63) >> 6;
    if (W == 0) return;
    int E = min(*ecnt_p, ECAP);
    for (int w = tid; w < W; w += 1024) {
        int rem = V - (w << 6);
        kA[w] = (rem >= 64) ? ~0ull : ((1ull << rem) - 1ull);
    }
    ull* cur = kA;
    ull* nxt = kB;
    __syncthreads();
    for (int round = 0; round <= V + 2; ++round) {
        for (int w = tid; w < W; w += 1024) sup[w] = 0ull;
        if (tid == 0) changed = 0;
        __syncthreads();
        for (int e = tid; e < E; e += 1024) {
            uint32_t pk = edges[e];
            int j = pk & 0xFFFF;
            int i = pk >> 16;
            if ((cur[j >> 6] >> (j & 63)) & 1ull)
                atomicOr(&sup[i >> 6], 1ull << (i & 63));
        }
        __syncthreads();
        for (int w = tid; w < W; w += 1024) {
            int rem = V - (w << 6);
            ull valid = (rem >= 64) ? ~0ull : ((1ull << rem) - 1ull);
            ull nk = valid & ~sup[w];
            nxt[w] = nk;
            if (nk != cur[w]) changed = 1;
        }
        __syncthreads();
        int ch = changed;
        __syncthreads();   // everyone reads `changed` before next round resets it
        ull* t = cur; cur = nxt; nxt = t;
        if (!ch) break;
    }
    for (int w = tid; w < W; w += 1024) {
        ull kwv = cur[w];
        int base = w << 6;
        for (int b = 0; b < 64; ++b) {
            int i = base + b;
            if (i < V) keep[i] = (int)((kwv >> b) & 1ull);
        }
    }
}

// Emit all rows: kept rows get data, everything else zeros (no d_out memset).
__global__ void __launch_bounds__(256)
out_kernel(const float* __restrict__ box, const float* __restrict__ conf,
           const int* __restrict__ cls, const int* __restrict__ order,
           const int* __restrict__ keep, const int* __restrict__ dV,
           float* __restrict__ out)
{
    int r = blockIdx.x * blockDim.x + threadIdx.x;
    if (r >= N_TOT) return;
    int V = *dV;
    float v0=0.f,v1=0.f,v2=0.f,v3=0.f,v4=0.f,v5=0.f;
    if (r < V && keep[r]) {
        int i = order[r];
        v0 = box[i*4+0]; v1 = box[i*4+1]; v2 = box[i*4+2]; v3 = box[i*4+3];
        v4 = conf[i];    v5 = (float)cls[i];
    }
    out[r*6+0]=v0; out[r*6+1]=v1; out[r*6+2]=v2;
    out[r*6+3]=v3; out[r*6+4]=v4; out[r*6+5]=v5;
}

extern "C" void kernel_launch(void* const* d_in, const int* in_sizes, int n_in,
                              void* d_out, int out_size, void* d_ws, size_t ws_size,
                              hipStream_t stream) {
    const float* p0 = (const float*)d_in[0];
    const float* p1 = (const float*)d_in[1];
    const float* p2 = (const float*)d_in[2];
    float* out = (float*)d_out;
    char* ws = (char*)d_ws;
    const int N = N_TOT;

    float* box   = (float*)ws;          // 4N
    float* conf  = box + 4*N;           // N
    float* score = conf + N;            // N
    float* sx1   = score + N;           // N
    float* sy1   = sx1 + N;             // N
    float* sx2   = sy1 + N;             // N
    float* sy2   = sx2 + N;             // N
    float* sarea = sy2 + N;             // N
    int* cls   = (int*)(sarea + N);     // N
    int* order = cls + N;               // N
    int* keep  = order + N;             // N
    int* scls  = keep + N;              // N
    int* rank42 = scls + N;             // 42N ints = 1.79 MB
    int* dV    = rank42 + (size_t)NB*N; // 1
    int* ecnt  = dV + 1;                // 1
    uintptr_t eaddr = ((uintptr_t)(ecnt + 1) + 15) & ~(uintptr_t)15;
    uint32_t* edges = (uint32_t*)eaddr; // ECAP u32 = 4 MB, last in ws

    hipMemsetAsync(dV, 0, 2 * sizeof(int), stream);   // dV and ecnt adjacent

    decode_kernel<<<NBD, 256, 0, stream>>>(p0, p1, p2, box, conf, score, cls, dV);
    rank_partial_kernel<<<dim3(NB, NB), 256, 0, stream>>>(score, rank42);
    scatter_gather_kernel<<<NB, 256, 0, stream>>>(box, cls, score, rank42, order,
                                                  sx1, sy1, sx2, sy2, sarea, scls);
    edge_kernel<<<dim3(NB, NB), 256, 0, stream>>>(sx1, sy1, sx2, sy2, sarea, scls,
                                                  dV, edges, ecnt);
    nms_sparse_kernel<<<1, 1024, 0, stream>>>(edges, ecnt, dV, keep);
    out_kernel<<<NB, 256, 0, stream>>>(box, conf, cls, order, keep, dV, out);
}

// Round 6
// 77.537 us; speedup vs baseline: 49.9784x; 1.1303x over previous
//
#include <hip/hip_runtime.h>
#include <stdint.h>

#define N_TOT 10647
#define MAXW  167        // ceil(10647/64)
#define NB    42         // ceil(10647/256)
#define NBD   167        // ceil(10647/64) decode blocks
#define NCLS  80
#define ECAP  (1 << 20)  // edge buffer cap (4 MB); expected E ~ 1e3-1e4

typedef unsigned long long ull;

// YOLOv3 COCO anchors, grouped by head: [0..2]=13x13, [3..5]=26x26, [6..8]=52x52
__constant__ float c_aw[9] = {116.f,156.f,373.f, 30.f,62.f,59.f, 10.f,16.f,33.f};
__constant__ float c_ah[9] = { 90.f,198.f,326.f, 61.f,45.f,119.f, 13.f,30.f,23.f};

__device__ __forceinline__ float sigmoidf_(float x) { return 1.0f / (1.0f + expf(-x)); }

// 4 threads per box: sub s (=tid>>6) scans classes [20s,20s+20); lane (=tid&63)
// picks the box. Strict '>' everywhere preserves jnp.argmax first-max-wins.
__global__ void __launch_bounds__(256)
decode_kernel(const float* __restrict__ p0, const float* __restrict__ p1,
              const float* __restrict__ p2,
              float* __restrict__ box, float* __restrict__ conf,
              float* __restrict__ score, int* __restrict__ cls,
              int* __restrict__ dV, int* __restrict__ ccount)
{
    __shared__ float sbest[4][64];
    __shared__ int   sbi[4][64];
    int sub  = threadIdx.x >> 6;
    int lane = threadIdx.x & 63;
    int n = blockIdx.x * 64 + lane;
    bool inb = (n < N_TOT);
    const float* p; int H, base, lvl; float stride;
    int nn = inb ? n : 0;
    if (nn < 507)       { p = p0; H = 13; base = 0;    stride = 32.f; lvl = 0; }
    else if (nn < 2535) { p = p1; H = 26; base = 507;  stride = 16.f; lvl = 1; }
    else                { p = p2; H = 52; base = 2535; stride = 8.f;  lvl = 2; }
    int m   = nn - base;
    int HW  = H * H;
    int a   = m / HW;
    int rem = m - a * HW;
    const float* q = p + (size_t)(a * 85) * HW + rem;
    float best = -3.4e38f; int bi = 20 * sub;
    if (inb) {
        int c0 = 20 * sub;
        #pragma unroll 5
        for (int c = c0; c < c0 + 20; ++c) {
            float v = q[(size_t)(5 + c) * HW];
            if (v > best) { best = v; bi = c; }
        }
    }
    sbest[sub][lane] = best;
    sbi[sub][lane]   = bi;
    __syncthreads();
    if (sub == 0 && inb) {
        float b0 = sbest[0][lane]; int i0 = sbi[0][lane];
        #pragma unroll
        for (int s = 1; s < 4; ++s) {
            float bs = sbest[s][lane];
            if (bs > b0) { b0 = bs; i0 = sbi[s][lane]; }
        }
        int gy = rem / H;
        int gx = rem - gy * H;
        float tx = q[0];
        float ty = q[(size_t)HW];
        float tw = q[(size_t)2*HW];
        float th = q[(size_t)3*HW];
        float tc = q[(size_t)4*HW];
        float cx = (sigmoidf_(tx) + (float)gx) * stride;
        float cy = (sigmoidf_(ty) + (float)gy) * stride;
        // exp(t)*(anchor/stride)*stride == exp(t)*anchor exactly (stride pow2)
        float bw = expf(tw) * c_aw[lvl*3 + a];
        float bh = expf(th) * c_ah[lvl*3 + a];
        float cf = sigmoidf_(tc);
        box[n*4+0] = cx; box[n*4+1] = cy; box[n*4+2] = bw; box[n*4+3] = bh;
        conf[n] = cf;
        cls[n]  = i0;
        bool valid = (cf >= 0.5f);
        score[n] = valid ? cf : -1.0f;
        if (valid) {
            atomicAdd(dV, 1);
            atomicAdd(&ccount[i0], 1);
        }
    }
}

// Partial stable-descending rank: block (bx,by) compares i-tile bx against
// j-tile by (staged in LDS). rank42[by*N + i] = partial count. No atomics.
__global__ void __launch_bounds__(256)
rank_partial_kernel(const float* __restrict__ score, int* __restrict__ rank42)
{
    __shared__ float tile[256];
    int tid = threadIdx.x;
    int i   = blockIdx.x * 256 + tid;
    int j0  = blockIdx.y * 256;
    int jj  = j0 + tid;
    tile[tid] = (jj < N_TOT) ? score[jj] : -2.0f;   // sentinel < all scores
    __syncthreads();
    float si = (i < N_TOT) ? score[i] : -2.0f;
    if (i >= N_TOT || si < 0.0f) return;            // invalid i: partial unused
    int r = 0;
    #pragma unroll 8
    for (int t = 0; t < 256; ++t) {
        float sj = tile[t];
        r += (sj > si || (sj == si && (j0 + t) < i)) ? 1 : 0;
    }
    rank42[(size_t)blockIdx.y * N_TOT + i] = r;
}

// Sum partial ranks, scatter order[r]=i, and gather corner/area/class arrays.
__global__ void __launch_bounds__(256)
scatter_gather_kernel(const float* __restrict__ box, const int* __restrict__ cls,
                      const float* __restrict__ score, const int* __restrict__ rank42,
                      int* __restrict__ order,
                      float* __restrict__ sx1, float* __restrict__ sy1,
                      float* __restrict__ sx2, float* __restrict__ sy2,
                      float* __restrict__ sarea, int* __restrict__ scls)
{
    int i = blockIdx.x * blockDim.x + threadIdx.x;
    if (i >= N_TOT) return;
    if (score[i] < 0.0f) return;
    int r = 0;
    #pragma unroll 6
    for (int s = 0; s < NB; ++s) r += rank42[(size_t)s * N_TOT + i];
    order[r] = i;
    float cx = box[i*4+0], cy = box[i*4+1], w = box[i*4+2], h = box[i*4+3];
    float hw = w * 0.5f, hh = h * 0.5f;
    sx1[r] = cx - hw; sy1[r] = cy - hh;
    sx2[r] = cx + hw; sy2[r] = cy + hh;
    sarea[r] = w * h;
    scls[r]  = cls[i];
}

// One block: 80-bin offsets (prefix over ccount), then bucket every sorted
// rank r into class_idx[coff[c]+pos] via LDS cursors. Bucket order is
// irrelevant: edge direction is decided by rank comparison later.
__global__ void __launch_bounds__(256)
class_fill_kernel(const int* __restrict__ scls, const int* __restrict__ dV,
                  const int* __restrict__ ccount, int* __restrict__ coff,
                  int* __restrict__ class_idx)
{
    __shared__ int loff[NCLS];
    __shared__ int lcur[NCLS];
    int tid = threadIdx.x;
    if (tid == 0) {
        int off = 0;
        for (int c = 0; c < NCLS; ++c) { loff[c] = off; off += ccount[c]; }
    }
    if (tid < NCLS) lcur[tid] = 0;
    __syncthreads();
    int V = *dV;
    for (int r = tid; r < V; r += 256) {
        int c = scls[r];
        int pos = atomicAdd(&lcur[c], 1);
        class_idx[loff[c] + pos] = r;
    }
    if (tid < NCLS) coff[tid] = loff[tid];
}

// Per-class all-pairs IoU (one block per class, tiled). Same class by
// construction; emit packed edge (i<<16|j) with j=min(ra,rb) < i=max(ra,rb).
__global__ void __launch_bounds__(256)
edge_class_kernel(const float* __restrict__ sx1, const float* __restrict__ sy1,
                  const float* __restrict__ sx2, const float* __restrict__ sy2,
                  const float* __restrict__ sarea,
                  const int* __restrict__ ccount, const int* __restrict__ coff,
                  const int* __restrict__ class_idx,
                  uint32_t* __restrict__ edges, int* __restrict__ ecnt)
{
    __shared__ float tx1[256], ty1[256], tx2[256], ty2[256], tar[256];
    __shared__ int   trk[256];
    int c   = blockIdx.x;
    int n   = ccount[c];
    int off = coff[c];
    int tid = threadIdx.x;
    for (int abase = 0; abase < n; abase += 256) {
        int a = abase + tid;
        bool ain = (a < n);
        int ra = 0; float ax1=0, ay1=0, ax2=0, ay2=0, aar=0;
        if (ain) {
            ra  = class_idx[off + a];
            ax1 = sx1[ra]; ay1 = sy1[ra];
            ax2 = sx2[ra]; ay2 = sy2[ra];
            aar = sarea[ra];
        }
        for (int bbase = 0; bbase <= abase; bbase += 256) {
            int b = bbase + tid;
            if (b < n) {
                int rb = class_idx[off + b];
                tx1[tid] = sx1[rb]; ty1[tid] = sy1[rb];
                tx2[tid] = sx2[rb]; ty2[tid] = sy2[rb];
                tar[tid] = sarea[rb]; trk[tid] = rb;
            }
            __syncthreads();
            int blim = min(256, n - bbase);
            int tlim = (bbase == abase) ? min(tid, blim) : blim;
            if (ain) {
                for (int t = 0; t < tlim; ++t) {
                    float xx1 = fmaxf(ax1, tx1[t]);
                    float yy1 = fmaxf(ay1, ty1[t]);
                    float xx2 = fminf(ax2, tx2[t]);
                    float yy2 = fminf(ay2, ty2[t]);
                    float w = fmaxf(xx2 - xx1, 0.0f);
                    float h = fmaxf(yy2 - yy1, 0.0f);
                    float inter = w * h;
                    float uni   = aar + tar[t] - inter;
                    float iou   = inter / fmaxf(uni, 1e-9f);
                    if (iou > 0.5f) {
                        int rb = trk[t];
                        uint32_t i = (uint32_t)max(ra, rb);
                        uint32_t j = (uint32_t)min(ra, rb);
                        int pos = atomicAdd(ecnt, 1);
                        if (pos < ECAP) edges[pos] = (i << 16) | j;
                    }
                }
            }
            __syncthreads();
        }
    }
}

// Sparse Jacobi fixpoint for greedy NMS, keep bitmap in LDS.
// keep_new[i] = valid[i] & !OR_{edges (j,i)} keep_prev[j].
// Zero-change round == unique fixpoint == greedy solution (induction over the
// index-ordered DAG); depth-d nodes final after d+1 rounds; cap V+2 => exact.
__global__ void __launch_bounds__(1024)
nms_sparse_kernel(const uint32_t* __restrict__ edges, const int* __restrict__ ecnt_p,
                  const int* __restrict__ dV, int* __restrict__ keep)
{
    __shared__ ull kA[MAXW], kB[MAXW], sup[MAXW];
    __shared__ int changed;
    int tid = threadIdx.x;
    int V = *dV;
    int W = (V + 63) >> 6;
    if (W == 0) return;
    int E = min(*ecnt_p, ECAP);
    for (int w = tid; w < W; w += 1024) {
        int rem = V - (w << 6);
        kA[w] = (rem >= 64) ? ~0ull : ((1ull << rem) - 1ull);
    }
    ull* cur = kA;
    ull* nxt = kB;
    __syncthreads();
    for (int round = 0; round <= V + 2; ++round) {
        for (int w = tid; w < W; w += 1024) sup[w] = 0ull;
        if (tid == 0) changed = 0;
        __syncthreads();
        for (int e = tid; e < E; e += 1024) {
            uint32_t pk = edges[e];
            int j = pk & 0xFFFF;
            int i = pk >> 16;
            if ((cur[j >> 6] >> (j & 63)) & 1ull)
                atomicOr(&sup[i >> 6], 1ull << (i & 63));
        }
        __syncthreads();
        for (int w = tid; w < W; w += 1024) {
            int rem = V - (w << 6);
            ull valid = (rem >= 64) ? ~0ull : ((1ull << rem) - 1ull);
            ull nk = valid & ~sup[w];
            nxt[w] = nk;
            if (nk != cur[w]) changed = 1;
        }
        __syncthreads();
        int ch = changed;
        __syncthreads();   // everyone reads `changed` before next round resets it
        ull* t = cur; cur = nxt; nxt = t;
        if (!ch) break;
    }
    for (int w = tid; w < W; w += 1024) {
        ull kwv = cur[w];
        int base = w << 6;
        for (int b = 0; b < 64; ++b) {
            int i = base + b;
            if (i < V) keep[i] = (int)((kwv >> b) & 1ull);
        }
    }
}

// Emit all rows: kept rows get data, everything else zeros (no d_out memset).
__global__ void __launch_bounds__(256)
out_kernel(const float* __restrict__ box, const float* __restrict__ conf,
           const int* __restrict__ cls, const int* __restrict__ order,
           const int* __restrict__ keep, const int* __restrict__ dV,
           float* __restrict__ out)
{
    int r = blockIdx.x * blockDim.x + threadIdx.x;
    if (r >= N_TOT) return;
    int V = *dV;
    float v0=0.f,v1=0.f,v2=0.f,v3=0.f,v4=0.f,v5=0.f;
    if (r < V && keep[r]) {
        int i = order[r];
        v0 = box[i*4+0]; v1 = box[i*4+1]; v2 = box[i*4+2]; v3 = box[i*4+3];
        v4 = conf[i];    v5 = (float)cls[i];
    }
    out[r*6+0]=v0; out[r*6+1]=v1; out[r*6+2]=v2;
    out[r*6+3]=v3; out[r*6+4]=v4; out[r*6+5]=v5;
}

extern "C" void kernel_launch(void* const* d_in, const int* in_sizes, int n_in,
                              void* d_out, int out_size, void* d_ws, size_t ws_size,
                              hipStream_t stream) {
    const float* p0 = (const float*)d_in[0];
    const float* p1 = (const float*)d_in[1];
    const float* p2 = (const float*)d_in[2];
    float* out = (float*)d_out;
    char* ws = (char*)d_ws;
    const int N = N_TOT;

    float* box   = (float*)ws;          // 4N
    float* conf  = box + 4*N;           // N
    float* score = conf + N;            // N
    float* sx1   = score + N;           // N
    float* sy1   = sx1 + N;             // N
    float* sx2   = sy1 + N;             // N
    float* sy2   = sx2 + N;             // N
    float* sarea = sy2 + N;             // N
    int* cls       = (int*)(sarea + N); // N
    int* order     = cls + N;           // N
    int* keep      = order + N;         // N
    int* scls      = keep + N;          // N
    int* class_idx = scls + N;          // N
    int* rank42    = class_idx + N;     // 42N ints = 1.79 MB
    int* dV     = rank42 + (size_t)NB*N; // 1
    int* ecnt   = dV + 1;               // 1
    int* ccount = ecnt + 1;             // 80
    int* coff   = ccount + NCLS;        // 80
    uintptr_t eaddr = ((uintptr_t)(coff + NCLS) + 15) & ~(uintptr_t)15;
    uint32_t* edges = (uint32_t*)eaddr; // ECAP u32 = 4 MB, last in ws

    // zero dV, ecnt, ccount (contiguous: 2 + 80 ints)
    hipMemsetAsync(dV, 0, (2 + NCLS) * sizeof(int), stream);

    decode_kernel<<<NBD, 256, 0, stream>>>(p0, p1, p2, box, conf, score, cls, dV, ccount);
    rank_partial_kernel<<<dim3(NB, NB), 256, 0, stream>>>(score, rank42);
    scatter_gather_kernel<<<NB, 256, 0, stream>>>(box, cls, score, rank42, order,
                                                  sx1, sy1, sx2, sy2, sarea, scls);
    class_fill_kernel<<<1, 256, 0, stream>>>(scls, dV, ccount, coff, class_idx);
    edge_class_kernel<<<NCLS, 256, 0, stream>>>(sx1, sy1, sx2, sy2, sarea,
                                                ccount, coff, class_idx, edges, ecnt);
    nms_sparse_kernel<<<1, 1024, 0, stream>>>(edges, ecnt, dV, keep);
    out_kernel<<<NB, 256, 0, stream>>>(box, conf, cls, order, keep, dV, out);
}